// Round 9
// baseline (284.768 us; speedup 1.0000x reference)
//
#include <hip/hip_runtime.h>
#include <hip/hip_bf16.h>
#include <math.h>

#define Bsz 4
#define Lsz 2048
#define Dsz 1024
#define Hn 16
#define HDsz 64
#define NQT 16  // Lsz/128

typedef __attribute__((ext_vector_type(8))) short short8;
typedef __attribute__((ext_vector_type(4))) float floatx4;
typedef __attribute__((ext_vector_type(2))) unsigned uint2v;
typedef unsigned short ushort_t;

__device__ __forceinline__ void load_lds_16B(const void* g, void* l) {
    __builtin_amdgcn_global_load_lds(
        (const __attribute__((address_space(1))) unsigned int*)g,
        (__attribute__((address_space(3))) unsigned int*)l, 16, 0, 0);
}

__device__ inline void cvt_store(float* p, size_t i, float v) { p[i] = v; }
__device__ inline void cvt_store(__hip_bfloat16* p, size_t i, float v) {
    p[i] = __float2bfloat16(v);
}

__device__ inline ushort_t f2bf_raw(float f) {
    __hip_bfloat16 b = __float2bfloat16(f);
    return *reinterpret_cast<ushort_t*>(&b);
}

__device__ inline float bf2f_raw(ushort_t u) {
    union { unsigned int i; float f; } c;
    c.i = ((unsigned int)u) << 16;
    return c.f;
}

__device__ __forceinline__ float fast_exp2(float x) {
#if __has_builtin(__builtin_amdgcn_exp2f)
    return __builtin_amdgcn_exp2f(x);  // raw v_exp_f32
#else
    return exp2f(x);
#endif
}

// fp32 -> bf16 for x (8192 blocks) and the 4 weight mats (4096 blocks).
__global__ __launch_bounds__(256) void f2ball(
    const float* __restrict__ x, const float* __restrict__ w0,
    const float* __restrict__ w1, const float* __restrict__ w2,
    const float* __restrict__ w3, __hip_bfloat16* __restrict__ xb,
    __hip_bfloat16* __restrict__ wb) {
    int bid = blockIdx.x;
    const float* in;
    __hip_bfloat16* o;
    size_t off;
    if (bid < 8192) {
        off = (size_t)bid * 1024 + threadIdx.x * 4;
        in = x;
        o = xb + off;
    } else {
        int b2 = bid - 8192;
        int sel = b2 >> 10;
        in = sel == 0 ? w0 : (sel == 1 ? w1 : (sel == 2 ? w2 : w3));
        off = (size_t)(b2 & 1023) * 1024 + threadIdx.x * 4;
        o = wb + (size_t)sel * (1024 * 1024) + off;
    }
    float4 v = *(const float4*)(in + off);
    o[0] = __float2bfloat16(v.x);
    o[1] = __float2bfloat16(v.y);
    o[2] = __float2bfloat16(v.z);
    o[3] = __float2bfloat16(v.w);
}

// ---------------------------------------------------------------------------
// BM=256 x BN=128, BK=64, 8-wave, TRIPLE-buffered 8-phase GEMM with counted
// vmcnt (T4).  v7: stage tile T+2 into buf (T+2)%3 during T (its readers
// were sealed at end of T-1); tile-end wait = vmcnt(6) -> only T+1's 6 loads
// (4 A + 2 B per thread, the oldest) must land, T+2's stay in flight.  Full
// drain only in the 2-tile epilogue.  LDS 144 KB -> still 1 block/CU.
// This replaces the old dbuf + vmcnt(0)-every-tile schedule, whose measured
// 652 TF sat exactly at the documented drain-0 level (m218/m230).
// ---------------------------------------------------------------------------
template <typename TO, bool QKV>
__global__ __launch_bounds__(512, 2) void gemm_bt_256(
    const ushort_t* __restrict__ A, const ushort_t* __restrict__ W,
    const float* __restrict__ b0, const float* __restrict__ b1,
    const float* __restrict__ b2, TO* __restrict__ C, int M, int N, int K) {
    __shared__ ushort_t As[3][256 * 64];  // 96 KB
    __shared__ ushort_t Bs[3][128 * 64];  // 48 KB

    const int t = threadIdx.x;
    const int wave = t >> 6, lane = t & 63;
    const int lmod = lane & 15, quad = lane >> 4;
    const int wm = wave >> 2, wn = wave & 3;  // 2M x 4N wave grid

    const int nbn = N >> 7;
    const int nwg = nbn * (M >> 8);
    const int bid = blockIdx.x;
    const int wg = (bid & 7) * (nwg >> 3) + (bid >> 3);
    const int n0 = (wg % nbn) * 128, m0 = (wg / nbn) * 256;

    floatx4 acc[2][2][4] = {};  // [mh][nh][mrep], nrep=1
    short8 Af[4][2], Bf[2];     // [rep][ks] / [ks]

    const int NT = K >> 6;  // 16

    auto stageA = [&](int kt, int bi) {
        const int kk = kt << 6;
#pragma unroll
        for (int p = 0; p < 4; p++) {
            int slot = t + p * 512;
            int row = slot >> 3, c8 = slot & 7;
            int gc8 = c8 ^ (row & 7);
            load_lds_16B(A + (size_t)(m0 + row) * K + kk + gc8 * 8,
                         &As[bi][slot * 8]);
        }
    };
    auto stageB = [&](int kt, int bi) {
        const int kk = kt << 6;
#pragma unroll
        for (int p = 0; p < 2; p++) {
            int slot = t + p * 512;
            int row = slot >> 3, c8 = slot & 7;
            int gc8 = c8 ^ (row & 7);
            load_lds_16B(W + (size_t)(n0 + row) * K + kk + gc8 * 8,
                         &Bs[bi][slot * 8]);
        }
    };
    auto rdA = [&](int bi, int mh) {
#pragma unroll
        for (int mr = 0; mr < 4; mr++) {
            int row = wm * 128 + mh * 64 + mr * 16 + lmod;
#pragma unroll
            for (int ks = 0; ks < 2; ks++) {
                int sc8 = (ks * 4 + quad) ^ (row & 7);
                Af[mr][ks] = *(const short8*)&As[bi][row * 64 + sc8 * 8];
            }
        }
    };
    auto rdB = [&](int bi, int nh) {
        int row = wn * 32 + nh * 16 + lmod;
#pragma unroll
        for (int ks = 0; ks < 2; ks++) {
            int sc8 = (ks * 4 + quad) ^ (row & 7);
            Bf[ks] = *(const short8*)&Bs[bi][row * 64 + sc8 * 8];
        }
    };
    auto domm = [&](int mh, int nh) {
        __builtin_amdgcn_s_setprio(1);
#pragma unroll
        for (int mr = 0; mr < 4; mr++)
#pragma unroll
            for (int ks = 0; ks < 2; ks++)
                acc[mh][nh][mr] = __builtin_amdgcn_mfma_f32_16x16x32_bf16(
                    Af[mr][ks], Bf[ks], acc[mh][nh][mr], 0, 0, 0);
        __builtin_amdgcn_s_setprio(0);
    };

    // prologue: T0 -> buf0, T1 -> buf1; wait only T0 (T1 stays in flight)
    stageA(0, 0);
    stageB(0, 0);
    stageA(1, 1);
    stageB(1, 1);
    asm volatile("s_waitcnt vmcnt(6)" ::: "memory");
    __builtin_amdgcn_s_barrier();
    asm volatile("" ::: "memory");

#pragma unroll 1
    for (int T = 0; T < NT; T++) {
        const int cur = T % 3;
        const bool pf = (T + 2 < NT);
        const int nb = (T + 2) % 3;
        // phase 1: (mh0,nh0); issue stage A(T+2)
        rdA(cur, 0);
        rdB(cur, 0);
        if (pf) stageA(T + 2, nb);
        __builtin_amdgcn_s_barrier();
        __builtin_amdgcn_sched_barrier(0);
        domm(0, 0);
        __builtin_amdgcn_s_barrier();
        // phase 2: (mh0,nh1); issue stage B(T+2)
        rdB(cur, 1);
        if (pf) stageB(T + 2, nb);
        __builtin_amdgcn_s_barrier();
        __builtin_amdgcn_sched_barrier(0);
        domm(0, 1);
        __builtin_amdgcn_s_barrier();
        // phase 3: (mh1,nh1)
        rdA(cur, 1);
        __builtin_amdgcn_s_barrier();
        __builtin_amdgcn_sched_barrier(0);
        domm(1, 1);
        __builtin_amdgcn_s_barrier();
        // phase 4: (mh1,nh0); counted tile-end wait: T+1's 6 loads land,
        // T+2's 6 remain in flight (vmcnt(6)); drain-0 only in epilogue.
        rdB(cur, 0);
        __builtin_amdgcn_s_barrier();
        __builtin_amdgcn_sched_barrier(0);
        domm(1, 0);
        if (pf)
            asm volatile("s_waitcnt vmcnt(6)" ::: "memory");
        else
            asm volatile("s_waitcnt vmcnt(0)" ::: "memory");
        __builtin_amdgcn_s_barrier();
        asm volatile("" ::: "memory");
    }

    const int sec = QKV ? (n0 >> 10) : 0;
    const float* bp = QKV ? (sec == 0 ? b0 : (sec == 1 ? b1 : b2)) : b0;
    TO* Cb = QKV ? (C + (size_t)sec * M * 1024) : C;
    const int Nout = QKV ? 1024 : N;
    const float sc = (QKV && sec == 0) ? 0.1803368801111204f : 1.0f;

#pragma unroll
    for (int mh = 0; mh < 2; mh++)
#pragma unroll
        for (int mr = 0; mr < 4; mr++) {
            int gm = m0 + wm * 128 + mh * 64 + mr * 16 + quad * 4;
#pragma unroll
            for (int nh = 0; nh < 2; nh++) {
                int gn = n0 + wn * 32 + nh * 16 + lmod;
                int cn = QKV ? (gn & 1023) : gn;
                float b = bp[cn];
#pragma unroll
                for (int r = 0; r < 4; r++)
                    cvt_store(Cb, (size_t)(gm + r) * Nout + cn,
                              (acc[mh][nh][mr][r] + b) * sc);
            }
        }
}

// MFMA flash attention, causal, fixed m=0, K-range split in 2 slices.
// (r7 verified: tr-read V path, cvt_pk P-pack, counted waits)  FROZEN.
__global__ __launch_bounds__(256) void attn_mfma(
    const ushort_t* __restrict__ q, const ushort_t* __restrict__ k,
    const ushort_t* __restrict__ v, ushort_t* __restrict__ Opart,
    float* __restrict__ lpart) {
    __shared__ ushort_t Ks[2][64 * 64];  // [buf][key][hd] swizzled, 16 KB
    __shared__ ushort_t Vs[64 * 64];     // [key][hd] swizzled, 8 KB
    __shared__ ushort_t Ps[4][32 * 64];  // per-wave [qrow(2x16)][key], 16 KB

    const int t = threadIdx.x;
    const int wave = t >> 6, lane = t & 63;
    const int lmod = lane & 15, quad = lane >> 4;

    // XCD-colocating decode: bid%8 = XCD = bh%8
    const int bid = blockIdx.x;
    const int j = bid >> 3;
    const int bx = j & 15;
    const int p = bx & 7, s = bx >> 3;
    const int bh = (bid & 7) + ((j >> 4) << 3);
    const int b = bh >> 4, h = bh & 15;
    const size_t base = ((size_t)b * Lsz) * Dsz + h * HDsz;

    ushort_t* Pw = (ushort_t*)Ps[wave];
    const int lm7 = lmod & 7;

    auto stageK = [&](int kt, int bi) {
#pragma unroll
        for (int pp = 0; pp < 2; pp++) {
            int slot = t + pp * 256;
            int row = slot >> 3, c8 = slot & 7;
            int gc8 = c8 ^ (row & 7);
            load_lds_16B(k + base + (size_t)(kt * 64 + row) * Dsz + gc8 * 8,
                         &Ks[bi][slot * 8]);
        }
    };
    auto stageV = [&](int kt) {
#pragma unroll
        for (int pp = 0; pp < 2; pp++) {
            int slot = t + pp * 256;
            int row = slot >> 3, c8 = slot & 7;
            int gc8 = c8 ^ (row & 7);
            load_lds_16B(v + base + (size_t)(kt * 64 + row) * Dsz + gc8 * 8,
                         &Vs[slot * 8]);
        }
    };

    const unsigned vsbase =
        (unsigned)(size_t)(__attribute__((address_space(3))) const ushort_t*)Vs;
    unsigned vaddr[2][2][4];  // [ks][jj][on]
    {
        const int lq = lmod >> 2;
        const int lmb = (lmod & 3) >> 1;
        const int lob = (lmod & 1) * 8;
#pragma unroll
        for (int ks = 0; ks < 2; ks++)
#pragma unroll
            for (int jj = 0; jj < 2; jj++) {
                int rowk = ks * 32 + quad * 8 + jj * 4 + lq;
                int r7 = rowk & 7;
#pragma unroll
                for (int on = 0; on < 4; on++)
                    vaddr[ks][jj][on] = vsbase + rowk * 128 +
                                        (((on * 2 + lmb) ^ r7) << 4) + lob;
            }
    }

    int bi = 0;

    stageK(s * (NQT - p), 0);

#pragma unroll 1
    for (int seg = 0; seg < 2; seg++) {
        const int qtile = seg == 0 ? (NQT - 1 - p) : p;
        const int q0 = qtile * 128;
        const int Th = qtile + 1;
        const int kt0 = s * Th, kt1 = kt0 + Th;
        const int kt0n = s * (p + 1);

        short8 aq[2][2];
#pragma unroll
        for (int g = 0; g < 2; g++) {
            const ushort_t* qp = q + base +
                                 (size_t)(q0 + wave * 32 + g * 16 + lmod) * Dsz +
                                 quad * 8;
            aq[g][0] = *(const short8*)(qp);
            aq[g][1] = *(const short8*)(qp + 32);
        }

        floatx4 Oacc[2][4] = {};
        float lsum[2] = {0.f, 0.f};

#pragma unroll 1
        for (int kt = kt0; kt < kt1; kt++) {
            asm volatile("s_waitcnt vmcnt(0)" ::: "memory");
            __builtin_amdgcn_s_barrier();
            asm volatile("" ::: "memory");

            stageV(kt);
            const int ktn = (kt + 1 < kt1) ? kt + 1 : (seg == 0 ? kt0n : -1);
            if (ktn >= 0) stageK(ktn, bi ^ 1);

            floatx4 St[2][4] = {};
#pragma unroll
            for (int nt = 0; nt < 4; nt++) {
                int key = nt * 16 + lmod;
#pragma unroll
                for (int ks = 0; ks < 2; ks++) {
                    int sc8 = (ks * 4 + quad) ^ (key & 7);
                    short8 kf = *(const short8*)&Ks[bi][(key * 8 + sc8) * 8];
#pragma unroll
                    for (int g = 0; g < 2; g++)
                        St[g][nt] = __builtin_amdgcn_mfma_f32_16x16x32_bf16(
                            kf, aq[g][ks], St[g][nt], 0, 0, 0);
                }
            }

            const bool need_mask = (kt >= 2 * qtile);
#pragma unroll
            for (int g = 0; g < 2; g++) {
                int qg = q0 + wave * 32 + g * 16 + lmod;
#pragma unroll
                for (int nt = 0; nt < 4; nt++) {
                    int k0g = kt * 64 + nt * 16 + quad * 4;
                    float p0 = fast_exp2(St[g][nt][0]);
                    float p1 = fast_exp2(St[g][nt][1]);
                    float p2 = fast_exp2(St[g][nt][2]);
                    float p3 = fast_exp2(St[g][nt][3]);
                    if (need_mask) {
                        if (k0g + 0 > qg) p0 = 0.f;
                        if (k0g + 1 > qg) p1 = 0.f;
                        if (k0g + 2 > qg) p2 = 0.f;
                        if (k0g + 3 > qg) p3 = 0.f;
                    }
                    lsum[g] += ((p0 + p1) + (p2 + p3));
                    unsigned wx, wy;
                    asm("v_cvt_pk_bf16_f32 %0, %1, %2"
                        : "=v"(wx)
                        : "v"(p0), "v"(p1));
                    asm("v_cvt_pk_bf16_f32 %0, %1, %2"
                        : "=v"(wy)
                        : "v"(p2), "v"(p3));
                    uint2 w;
                    w.x = wx;
                    w.y = wy;
                    int c8 = nt * 2 + (quad >> 1);
                    int sc8 = c8 ^ lm7;
                    *(uint2*)&Pw[((g * 16 + lmod) * 8 + sc8) * 8 +
                                 (quad & 1) * 4] = w;
                }
            }

            short8 ap[2][2];
#pragma unroll
            for (int g = 0; g < 2; g++)
#pragma unroll
                for (int ks = 0; ks < 2; ks++) {
                    int sc8 = (ks * 4 + quad) ^ lm7;
                    ap[g][ks] =
                        *(const short8*)&Pw[((g * 16 + lmod) * 8 + sc8) * 8];
                }

            if (ktn >= 0)
                asm volatile("s_waitcnt vmcnt(2)" ::: "memory");
            else
                asm volatile("s_waitcnt vmcnt(0)" ::: "memory");
            __builtin_amdgcn_s_barrier();
            asm volatile("" ::: "memory");

#pragma unroll
            for (int on = 0; on < 4; on++) {
                uint2v t00, t01, t10, t11;
                asm volatile("ds_read_b64_tr_b16 %0, %1"
                             : "=v"(t00)
                             : "v"(vaddr[0][0][on]));
                asm volatile("ds_read_b64_tr_b16 %0, %1"
                             : "=v"(t01)
                             : "v"(vaddr[0][1][on]));
                asm volatile("ds_read_b64_tr_b16 %0, %1"
                             : "=v"(t10)
                             : "v"(vaddr[1][0][on]));
                asm volatile("ds_read_b64_tr_b16 %0, %1"
                             : "=v"(t11)
                             : "v"(vaddr[1][1][on]));
                asm volatile("s_waitcnt lgkmcnt(0)" ::: "memory");
                __builtin_amdgcn_sched_barrier(0);
                union U { uint2v pr[2]; short8 s8; } u0, u1;
                u0.pr[0] = t00;
                u0.pr[1] = t01;
                u1.pr[0] = t10;
                u1.pr[1] = t11;
#pragma unroll
                for (int g = 0; g < 2; g++) {
                    Oacc[g][on] = __builtin_amdgcn_mfma_f32_16x16x32_bf16(
                        ap[g][0], u0.s8, Oacc[g][on], 0, 0, 0);
                    Oacc[g][on] = __builtin_amdgcn_mfma_f32_16x16x32_bf16(
                        ap[g][1], u1.s8, Oacc[g][on], 0, 0, 0);
                }
            }

            bi ^= 1;
        }

#pragma unroll
        for (int g = 0; g < 2; g++) {
            lsum[g] += __shfl_xor(lsum[g], 16);
            lsum[g] += __shfl_xor(lsum[g], 32);
        }

        const size_t rec = ((size_t)bh * NQT + qtile) * 2 + s;
        ushort_t* Orec = Opart + rec * (128 * 64);
        float* lrec = lpart + rec * 128;
#pragma unroll
        for (int g = 0; g < 2; g++) {
            if (quad == 0) lrec[wave * 32 + g * 16 + lmod] = lsum[g];
#pragma unroll
            for (int r = 0; r < 4; r++) {
                int row = wave * 32 + g * 16 + quad * 4 + r;
#pragma unroll
                for (int on = 0; on < 4; on++) {
                    int d = on * 16 + lmod;
                    Orec[row * 64 + d] = f2bf_raw(Oacc[g][on][r]);
                }
            }
        }
    }
}

// ao[b][qg][h*64+d] = (O0+O1)/(l0+l1); one thread per 8 cols.
__global__ __launch_bounds__(256) void attn_combine(
    const ushort_t* __restrict__ Opart, const float* __restrict__ lpart,
    ushort_t* __restrict__ ao) {
    int gidx = blockIdx.x * 256 + threadIdx.x;
    int rowglob = gidx >> 3;
    int c8 = (gidx & 7) * 8;
    int bh = rowglob >> 11;
    int r11 = rowglob & 2047;
    int qtile = r11 >> 7, row = r11 & 127;

    size_t rec0 = ((size_t)bh * NQT + qtile) * 2;
    const ushort_t* O0 = Opart + (rec0 + 0) * (128 * 64) + row * 64 + c8;
    const ushort_t* O1 = Opart + (rec0 + 1) * (128 * 64) + row * 64 + c8;
    float l = lpart[(rec0 + 0) * 128 + row] + lpart[(rec0 + 1) * 128 + row];
    float inv = 1.0f / l;

    short8 a = *(const short8*)O0;
    short8 bvec = *(const short8*)O1;
    short8 o;
#pragma unroll
    for (int j = 0; j < 8; j++) {
        float vv = (bf2f_raw((ushort_t)a[j]) + bf2f_raw((ushort_t)bvec[j])) * inv;
        o[j] = (short)f2bf_raw(vv);
    }
    int b = bh >> 4, h = bh & 15;
    int qg = qtile * 128 + row;
    *(short8*)&ao[((size_t)(b * Lsz + qg)) * Dsz + h * HDsz + c8] = o;
}

extern "C" void kernel_launch(void* const* d_in, const int* in_sizes, int n_in,
                              void* d_out, int out_size, void* d_ws,
                              size_t ws_size, hipStream_t stream) {
    const size_t elems = (size_t)Bsz * Lsz * Dsz;  // 8.4M
    const size_t welem = (size_t)Dsz * Dsz;        // 1M
    const size_t nrec = (size_t)Bsz * Hn * NQT * 2;  // 2048
    const size_t opart_e = nrec * 128 * 64;          // 16.8M bf16
    const size_t need = (5 * elems + 4 * welem + opart_e) * 2 + nrec * 128 * 4;
    if (ws_size < need) return;  // ~121 MB

    const float* x = (const float*)d_in[0];
    const float* Wq = (const float*)d_in[1];
    const float* bq = (const float*)d_in[2];
    const float* Wk = (const float*)d_in[3];
    const float* bk = (const float*)d_in[4];
    const float* Wv = (const float*)d_in[5];
    const float* bv = (const float*)d_in[6];
    const float* Wo = (const float*)d_in[7];
    const float* bo = (const float*)d_in[8];
    float* out = (float*)d_out;

    __hip_bfloat16* xb = (__hip_bfloat16*)d_ws;
    __hip_bfloat16* q = xb + elems;
    __hip_bfloat16* k = q + elems;   // q,k,v contiguous: QKV-GEMM target
    __hip_bfloat16* v = k + elems;
    __hip_bfloat16* ao = v + elems;
    __hip_bfloat16* Wqb = ao + elems;  // Wq,Wk,Wv contiguous: [3072][1024]
    __hip_bfloat16* Wkb = Wqb + welem;
    __hip_bfloat16* Wvb = Wkb + welem;
    __hip_bfloat16* Wob = Wvb + welem;
    ushort_t* Opart = (ushort_t*)(Wob + welem);
    float* lpart = (float*)(Opart + opart_e);

    const int M = Bsz * Lsz, N = Dsz, K = Dsz;

    // single conversion launch: x (8192 blocks) + 4 weights (4096 blocks)
    f2ball<<<12288, 256, 0, stream>>>(x, Wq, Wk, Wv, Wo, xb, Wqb);

    // QKV: 256x128-tile counted-vmcnt 8-phase kernel, grid 768 = 3 rounds
    gemm_bt_256<__hip_bfloat16, true><<<(3 * N / 128) * (M / 256), 512, 0,
                                        stream>>>(
        (const ushort_t*)xb, (const ushort_t*)Wqb, bq, bk, bv, q, M, 3 * N, K);

    attn_mfma<<<16 * Bsz * Hn, 256, 0, stream>>>(
        (const ushort_t*)q, (const ushort_t*)k, (const ushort_t*)v, Opart,
        lpart);

    attn_combine<<<(int)(elems / 8 / 256), 256, 0, stream>>>(Opart, lpart,
                                                             (ushort_t*)ao);

    // out-proj: same counted-vmcnt kernel, grid 256 = 1 round
    gemm_bt_256<float, false><<<(N / 128) * (M / 256), 512, 0, stream>>>(
        (const ushort_t*)ao, (const ushort_t*)Wob, bo, bo, bo, out, M, N, K);
}

// Round 10
// 266.273 us; speedup vs baseline: 1.0695x; 1.0695x over previous
//
#include <hip/hip_runtime.h>
#include <hip/hip_bf16.h>
#include <math.h>

#define Bsz 4
#define Lsz 2048
#define Dsz 1024
#define Hn 16
#define HDsz 64
#define NQT 16  // Lsz/128

typedef __attribute__((ext_vector_type(8))) short short8;
typedef __attribute__((ext_vector_type(4))) float floatx4;
typedef __attribute__((ext_vector_type(2))) unsigned uint2v;
typedef unsigned short ushort_t;

__device__ __forceinline__ void load_lds_16B(const void* g, void* l) {
    __builtin_amdgcn_global_load_lds(
        (const __attribute__((address_space(1))) unsigned int*)g,
        (__attribute__((address_space(3))) unsigned int*)l, 16, 0, 0);
}

__device__ inline void cvt_store(float* p, size_t i, float v) { p[i] = v; }
__device__ inline void cvt_store(__hip_bfloat16* p, size_t i, float v) {
    p[i] = __float2bfloat16(v);
}

__device__ inline ushort_t f2bf_raw(float f) {
    __hip_bfloat16 b = __float2bfloat16(f);
    return *reinterpret_cast<ushort_t*>(&b);
}

__device__ inline float bf2f_raw(ushort_t u) {
    union { unsigned int i; float f; } c;
    c.i = ((unsigned int)u) << 16;
    return c.f;
}

__device__ __forceinline__ float fast_exp2(float x) {
#if __has_builtin(__builtin_amdgcn_exp2f)
    return __builtin_amdgcn_exp2f(x);  // raw v_exp_f32
#else
    return exp2f(x);
#endif
}

// fp32 -> bf16 for x (8192 blocks) and the 4 weight mats (4096 blocks).
__global__ __launch_bounds__(256) void f2ball(
    const float* __restrict__ x, const float* __restrict__ w0,
    const float* __restrict__ w1, const float* __restrict__ w2,
    const float* __restrict__ w3, __hip_bfloat16* __restrict__ xb,
    __hip_bfloat16* __restrict__ wb) {
    int bid = blockIdx.x;
    const float* in;
    __hip_bfloat16* o;
    size_t off;
    if (bid < 8192) {
        off = (size_t)bid * 1024 + threadIdx.x * 4;
        in = x;
        o = xb + off;
    } else {
        int b2 = bid - 8192;
        int sel = b2 >> 10;
        in = sel == 0 ? w0 : (sel == 1 ? w1 : (sel == 2 ? w2 : w3));
        off = (size_t)(b2 & 1023) * 1024 + threadIdx.x * 4;
        o = wb + (size_t)sel * (1024 * 1024) + off;
    }
    float4 v = *(const float4*)(in + off);
    o[0] = __float2bfloat16(v.x);
    o[1] = __float2bfloat16(v.y);
    o[2] = __float2bfloat16(v.z);
    o[3] = __float2bfloat16(v.w);
}

// ---------------------------------------------------------------------------
// BM=256 x BN=128, BK=64, 8-wave, double-buffered, MINIMAL-barrier GEMM.
// v8: one s_barrier per K-tile (was 8).  r8/r9 showed 8-phase barriers and
// counted-vmcnt both measure at/below the 2-phase level for this K=1024
// shape -> the phase machinery is pure overhead here.  Schedule per tile:
// read all cur fragments, issue both next-tile stages into nxt, 32 MFMA
// (setprio-wrapped, mh1 A-frags reloaded mid-block to cap VGPR), then the
// tile's single vmcnt(0)+s_barrier (seals nxt before it becomes cur; prior
// tile's barrier sealed cur's readers before nxt-staging).
// ---------------------------------------------------------------------------
template <typename TO, bool QKV>
__global__ __launch_bounds__(512, 2) void gemm_bt_256(
    const ushort_t* __restrict__ A, const ushort_t* __restrict__ W,
    const float* __restrict__ b0, const float* __restrict__ b1,
    const float* __restrict__ b2, TO* __restrict__ C, int M, int N, int K) {
    __shared__ ushort_t As[2][256 * 64];  // 64 KB
    __shared__ ushort_t Bs[2][128 * 64];  // 32 KB

    const int t = threadIdx.x;
    const int wave = t >> 6, lane = t & 63;
    const int lmod = lane & 15, quad = lane >> 4;
    const int wm = wave >> 2, wn = wave & 3;  // 2M x 4N wave grid

    const int nbn = N >> 7;
    const int nwg = nbn * (M >> 8);
    const int bid = blockIdx.x;
    const int wg = (bid & 7) * (nwg >> 3) + (bid >> 3);
    const int n0 = (wg % nbn) * 128, m0 = (wg / nbn) * 256;

    floatx4 acc[2][2][4] = {};  // [mh][nh][mrep]
    short8 Af[4][2], Bf[2][2];  // [mrep][ks] / [nh][ks]

    const int NT = K >> 6;  // 16

    auto stageA = [&](int kt, int bi) {
        const int kk = kt << 6;
#pragma unroll
        for (int p = 0; p < 4; p++) {
            int slot = t + p * 512;
            int row = slot >> 3, c8 = slot & 7;
            int gc8 = c8 ^ (row & 7);
            load_lds_16B(A + (size_t)(m0 + row) * K + kk + gc8 * 8,
                         &As[bi][slot * 8]);
        }
    };
    auto stageB = [&](int kt, int bi) {
        const int kk = kt << 6;
#pragma unroll
        for (int p = 0; p < 2; p++) {
            int slot = t + p * 512;
            int row = slot >> 3, c8 = slot & 7;
            int gc8 = c8 ^ (row & 7);
            load_lds_16B(W + (size_t)(n0 + row) * K + kk + gc8 * 8,
                         &Bs[bi][slot * 8]);
        }
    };
    auto rdA = [&](int bi, int mh) {
#pragma unroll
        for (int mr = 0; mr < 4; mr++) {
            int row = wm * 128 + mh * 64 + mr * 16 + lmod;
#pragma unroll
            for (int ks = 0; ks < 2; ks++) {
                int sc8 = (ks * 4 + quad) ^ (row & 7);
                Af[mr][ks] = *(const short8*)&As[bi][row * 64 + sc8 * 8];
            }
        }
    };
    auto rdB = [&](int bi, int nh) {
        int row = wn * 32 + nh * 16 + lmod;
#pragma unroll
        for (int ks = 0; ks < 2; ks++) {
            int sc8 = (ks * 4 + quad) ^ (row & 7);
            Bf[nh][ks] = *(const short8*)&Bs[bi][row * 64 + sc8 * 8];
        }
    };
    auto domm = [&](int mh, int nh) {
        __builtin_amdgcn_s_setprio(1);
#pragma unroll
        for (int mr = 0; mr < 4; mr++)
#pragma unroll
            for (int ks = 0; ks < 2; ks++)
                acc[mh][nh][mr] = __builtin_amdgcn_mfma_f32_16x16x32_bf16(
                    Af[mr][ks], Bf[nh][ks], acc[mh][nh][mr], 0, 0, 0);
        __builtin_amdgcn_s_setprio(0);
    };

    // prologue: T0 -> buf 0
    stageA(0, 0);
    stageB(0, 0);
    asm volatile("s_waitcnt vmcnt(0)" ::: "memory");
    __builtin_amdgcn_s_barrier();
    asm volatile("" ::: "memory");

#pragma unroll 1
    for (int T = 0; T < NT; T++) {
        const int cur = T & 1, nxt = cur ^ 1;
        const bool pf = (T + 1 < NT);
        // all cur-fragment reads + both next-tile stage issues, no barriers
        rdA(cur, 0);
        rdB(cur, 0);
        rdB(cur, 1);
        if (pf) {
            stageA(T + 1, nxt);
            stageB(T + 1, nxt);
        }
        domm(0, 0);
        domm(0, 1);
        rdA(cur, 1);  // mh1 A-frags reload (overlaps mh0 MFMAs)
        domm(1, 0);
        domm(1, 1);
        // single per-tile rendezvous: my stage ops landed (vmcnt), all
        // waves' cur reads done (barrier) -> nxt may become cur
        asm volatile("s_waitcnt vmcnt(0)" ::: "memory");
        __builtin_amdgcn_s_barrier();
        asm volatile("" ::: "memory");
    }

    const int sec = QKV ? (n0 >> 10) : 0;
    const float* bp = QKV ? (sec == 0 ? b0 : (sec == 1 ? b1 : b2)) : b0;
    TO* Cb = QKV ? (C + (size_t)sec * M * 1024) : C;
    const int Nout = QKV ? 1024 : N;
    const float sc = (QKV && sec == 0) ? 0.1803368801111204f : 1.0f;

#pragma unroll
    for (int mh = 0; mh < 2; mh++)
#pragma unroll
        for (int mr = 0; mr < 4; mr++) {
            int gm = m0 + wm * 128 + mh * 64 + mr * 16 + quad * 4;
#pragma unroll
            for (int nh = 0; nh < 2; nh++) {
                int gn = n0 + wn * 32 + nh * 16 + lmod;
                int cn = QKV ? (gn & 1023) : gn;
                float b = bp[cn];
#pragma unroll
                for (int r = 0; r < 4; r++)
                    cvt_store(Cb, (size_t)(gm + r) * Nout + cn,
                              (acc[mh][nh][mr][r] + b) * sc);
            }
        }
}

// MFMA flash attention, causal, fixed m=0, K-range split in 2 slices.
// (r7 verified: tr-read V path, cvt_pk P-pack, counted waits)  FROZEN.
__global__ __launch_bounds__(256) void attn_mfma(
    const ushort_t* __restrict__ q, const ushort_t* __restrict__ k,
    const ushort_t* __restrict__ v, ushort_t* __restrict__ Opart,
    float* __restrict__ lpart) {
    __shared__ ushort_t Ks[2][64 * 64];  // [buf][key][hd] swizzled, 16 KB
    __shared__ ushort_t Vs[64 * 64];     // [key][hd] swizzled, 8 KB
    __shared__ ushort_t Ps[4][32 * 64];  // per-wave [qrow(2x16)][key], 16 KB

    const int t = threadIdx.x;
    const int wave = t >> 6, lane = t & 63;
    const int lmod = lane & 15, quad = lane >> 4;

    // XCD-colocating decode: bid%8 = XCD = bh%8
    const int bid = blockIdx.x;
    const int j = bid >> 3;
    const int bx = j & 15;
    const int p = bx & 7, s = bx >> 3;
    const int bh = (bid & 7) + ((j >> 4) << 3);
    const int b = bh >> 4, h = bh & 15;
    const size_t base = ((size_t)b * Lsz) * Dsz + h * HDsz;

    ushort_t* Pw = (ushort_t*)Ps[wave];
    const int lm7 = lmod & 7;

    auto stageK = [&](int kt, int bi) {
#pragma unroll
        for (int pp = 0; pp < 2; pp++) {
            int slot = t + pp * 256;
            int row = slot >> 3, c8 = slot & 7;
            int gc8 = c8 ^ (row & 7);
            load_lds_16B(k + base + (size_t)(kt * 64 + row) * Dsz + gc8 * 8,
                         &Ks[bi][slot * 8]);
        }
    };
    auto stageV = [&](int kt) {
#pragma unroll
        for (int pp = 0; pp < 2; pp++) {
            int slot = t + pp * 256;
            int row = slot >> 3, c8 = slot & 7;
            int gc8 = c8 ^ (row & 7);
            load_lds_16B(v + base + (size_t)(kt * 64 + row) * Dsz + gc8 * 8,
                         &Vs[slot * 8]);
        }
    };

    const unsigned vsbase =
        (unsigned)(size_t)(__attribute__((address_space(3))) const ushort_t*)Vs;
    unsigned vaddr[2][2][4];  // [ks][jj][on]
    {
        const int lq = lmod >> 2;
        const int lmb = (lmod & 3) >> 1;
        const int lob = (lmod & 1) * 8;
#pragma unroll
        for (int ks = 0; ks < 2; ks++)
#pragma unroll
            for (int jj = 0; jj < 2; jj++) {
                int rowk = ks * 32 + quad * 8 + jj * 4 + lq;
                int r7 = rowk & 7;
#pragma unroll
                for (int on = 0; on < 4; on++)
                    vaddr[ks][jj][on] = vsbase + rowk * 128 +
                                        (((on * 2 + lmb) ^ r7) << 4) + lob;
            }
    }

    int bi = 0;

    stageK(s * (NQT - p), 0);

#pragma unroll 1
    for (int seg = 0; seg < 2; seg++) {
        const int qtile = seg == 0 ? (NQT - 1 - p) : p;
        const int q0 = qtile * 128;
        const int Th = qtile + 1;
        const int kt0 = s * Th, kt1 = kt0 + Th;
        const int kt0n = s * (p + 1);

        short8 aq[2][2];
#pragma unroll
        for (int g = 0; g < 2; g++) {
            const ushort_t* qp = q + base +
                                 (size_t)(q0 + wave * 32 + g * 16 + lmod) * Dsz +
                                 quad * 8;
            aq[g][0] = *(const short8*)(qp);
            aq[g][1] = *(const short8*)(qp + 32);
        }

        floatx4 Oacc[2][4] = {};
        float lsum[2] = {0.f, 0.f};

#pragma unroll 1
        for (int kt = kt0; kt < kt1; kt++) {
            asm volatile("s_waitcnt vmcnt(0)" ::: "memory");
            __builtin_amdgcn_s_barrier();
            asm volatile("" ::: "memory");

            stageV(kt);
            const int ktn = (kt + 1 < kt1) ? kt + 1 : (seg == 0 ? kt0n : -1);
            if (ktn >= 0) stageK(ktn, bi ^ 1);

            floatx4 St[2][4] = {};
#pragma unroll
            for (int nt = 0; nt < 4; nt++) {
                int key = nt * 16 + lmod;
#pragma unroll
                for (int ks = 0; ks < 2; ks++) {
                    int sc8 = (ks * 4 + quad) ^ (key & 7);
                    short8 kf = *(const short8*)&Ks[bi][(key * 8 + sc8) * 8];
#pragma unroll
                    for (int g = 0; g < 2; g++)
                        St[g][nt] = __builtin_amdgcn_mfma_f32_16x16x32_bf16(
                            kf, aq[g][ks], St[g][nt], 0, 0, 0);
                }
            }

            const bool need_mask = (kt >= 2 * qtile);
#pragma unroll
            for (int g = 0; g < 2; g++) {
                int qg = q0 + wave * 32 + g * 16 + lmod;
#pragma unroll
                for (int nt = 0; nt < 4; nt++) {
                    int k0g = kt * 64 + nt * 16 + quad * 4;
                    float p0 = fast_exp2(St[g][nt][0]);
                    float p1 = fast_exp2(St[g][nt][1]);
                    float p2 = fast_exp2(St[g][nt][2]);
                    float p3 = fast_exp2(St[g][nt][3]);
                    if (need_mask) {
                        if (k0g + 0 > qg) p0 = 0.f;
                        if (k0g + 1 > qg) p1 = 0.f;
                        if (k0g + 2 > qg) p2 = 0.f;
                        if (k0g + 3 > qg) p3 = 0.f;
                    }
                    lsum[g] += ((p0 + p1) + (p2 + p3));
                    unsigned wx, wy;
                    asm("v_cvt_pk_bf16_f32 %0, %1, %2"
                        : "=v"(wx)
                        : "v"(p0), "v"(p1));
                    asm("v_cvt_pk_bf16_f32 %0, %1, %2"
                        : "=v"(wy)
                        : "v"(p2), "v"(p3));
                    uint2 w;
                    w.x = wx;
                    w.y = wy;
                    int c8 = nt * 2 + (quad >> 1);
                    int sc8 = c8 ^ lm7;
                    *(uint2*)&Pw[((g * 16 + lmod) * 8 + sc8) * 8 +
                                 (quad & 1) * 4] = w;
                }
            }

            short8 ap[2][2];
#pragma unroll
            for (int g = 0; g < 2; g++)
#pragma unroll
                for (int ks = 0; ks < 2; ks++) {
                    int sc8 = (ks * 4 + quad) ^ lm7;
                    ap[g][ks] =
                        *(const short8*)&Pw[((g * 16 + lmod) * 8 + sc8) * 8];
                }

            if (ktn >= 0)
                asm volatile("s_waitcnt vmcnt(2)" ::: "memory");
            else
                asm volatile("s_waitcnt vmcnt(0)" ::: "memory");
            __builtin_amdgcn_s_barrier();
            asm volatile("" ::: "memory");

#pragma unroll
            for (int on = 0; on < 4; on++) {
                uint2v t00, t01, t10, t11;
                asm volatile("ds_read_b64_tr_b16 %0, %1"
                             : "=v"(t00)
                             : "v"(vaddr[0][0][on]));
                asm volatile("ds_read_b64_tr_b16 %0, %1"
                             : "=v"(t01)
                             : "v"(vaddr[0][1][on]));
                asm volatile("ds_read_b64_tr_b16 %0, %1"
                             : "=v"(t10)
                             : "v"(vaddr[1][0][on]));
                asm volatile("ds_read_b64_tr_b16 %0, %1"
                             : "=v"(t11)
                             : "v"(vaddr[1][1][on]));
                asm volatile("s_waitcnt lgkmcnt(0)" ::: "memory");
                __builtin_amdgcn_sched_barrier(0);
                union U { uint2v pr[2]; short8 s8; } u0, u1;
                u0.pr[0] = t00;
                u0.pr[1] = t01;
                u1.pr[0] = t10;
                u1.pr[1] = t11;
#pragma unroll
                for (int g = 0; g < 2; g++) {
                    Oacc[g][on] = __builtin_amdgcn_mfma_f32_16x16x32_bf16(
                        ap[g][0], u0.s8, Oacc[g][on], 0, 0, 0);
                    Oacc[g][on] = __builtin_amdgcn_mfma_f32_16x16x32_bf16(
                        ap[g][1], u1.s8, Oacc[g][on], 0, 0, 0);
                }
            }

            bi ^= 1;
        }

#pragma unroll
        for (int g = 0; g < 2; g++) {
            lsum[g] += __shfl_xor(lsum[g], 16);
            lsum[g] += __shfl_xor(lsum[g], 32);
        }

        const size_t rec = ((size_t)bh * NQT + qtile) * 2 + s;
        ushort_t* Orec = Opart + rec * (128 * 64);
        float* lrec = lpart + rec * 128;
#pragma unroll
        for (int g = 0; g < 2; g++) {
            if (quad == 0) lrec[wave * 32 + g * 16 + lmod] = lsum[g];
#pragma unroll
            for (int r = 0; r < 4; r++) {
                int row = wave * 32 + g * 16 + quad * 4 + r;
#pragma unroll
                for (int on = 0; on < 4; on++) {
                    int d = on * 16 + lmod;
                    Orec[row * 64 + d] = f2bf_raw(Oacc[g][on][r]);
                }
            }
        }
    }
}

// ao[b][qg][h*64+d] = (O0+O1)/(l0+l1); one thread per 8 cols.
__global__ __launch_bounds__(256) void attn_combine(
    const ushort_t* __restrict__ Opart, const float* __restrict__ lpart,
    ushort_t* __restrict__ ao) {
    int gidx = blockIdx.x * 256 + threadIdx.x;
    int rowglob = gidx >> 3;
    int c8 = (gidx & 7) * 8;
    int bh = rowglob >> 11;
    int r11 = rowglob & 2047;
    int qtile = r11 >> 7, row = r11 & 127;

    size_t rec0 = ((size_t)bh * NQT + qtile) * 2;
    const ushort_t* O0 = Opart + (rec0 + 0) * (128 * 64) + row * 64 + c8;
    const ushort_t* O1 = Opart + (rec0 + 1) * (128 * 64) + row * 64 + c8;
    float l = lpart[(rec0 + 0) * 128 + row] + lpart[(rec0 + 1) * 128 + row];
    float inv = 1.0f / l;

    short8 a = *(const short8*)O0;
    short8 bvec = *(const short8*)O1;
    short8 o;
#pragma unroll
    for (int j = 0; j < 8; j++) {
        float vv = (bf2f_raw((ushort_t)a[j]) + bf2f_raw((ushort_t)bvec[j])) * inv;
        o[j] = (short)f2bf_raw(vv);
    }
    int b = bh >> 4, h = bh & 15;
    int qg = qtile * 128 + row;
    *(short8*)&ao[((size_t)(b * Lsz + qg)) * Dsz + h * HDsz + c8] = o;
}

extern "C" void kernel_launch(void* const* d_in, const int* in_sizes, int n_in,
                              void* d_out, int out_size, void* d_ws,
                              size_t ws_size, hipStream_t stream) {
    const size_t elems = (size_t)Bsz * Lsz * Dsz;  // 8.4M
    const size_t welem = (size_t)Dsz * Dsz;        // 1M
    const size_t nrec = (size_t)Bsz * Hn * NQT * 2;  // 2048
    const size_t opart_e = nrec * 128 * 64;          // 16.8M bf16
    const size_t need = (5 * elems + 4 * welem + opart_e) * 2 + nrec * 128 * 4;
    if (ws_size < need) return;  // ~121 MB

    const float* x = (const float*)d_in[0];
    const float* Wq = (const float*)d_in[1];
    const float* bq = (const float*)d_in[2];
    const float* Wk = (const float*)d_in[3];
    const float* bk = (const float*)d_in[4];
    const float* Wv = (const float*)d_in[5];
    const float* bv = (const float*)d_in[6];
    const float* Wo = (const float*)d_in[7];
    const float* bo = (const float*)d_in[8];
    float* out = (float*)d_out;

    __hip_bfloat16* xb = (__hip_bfloat16*)d_ws;
    __hip_bfloat16* q = xb + elems;
    __hip_bfloat16* k = q + elems;   // q,k,v contiguous: QKV-GEMM target
    __hip_bfloat16* v = k + elems;
    __hip_bfloat16* ao = v + elems;
    __hip_bfloat16* Wqb = ao + elems;  // Wq,Wk,Wv contiguous: [3072][1024]
    __hip_bfloat16* Wkb = Wqb + welem;
    __hip_bfloat16* Wvb = Wkb + welem;
    __hip_bfloat16* Wob = Wvb + welem;
    ushort_t* Opart = (ushort_t*)(Wob + welem);
    float* lpart = (float*)(Opart + opart_e);

    const int M = Bsz * Lsz, N = Dsz, K = Dsz;

    // single conversion launch: x (8192 blocks) + 4 weights (4096 blocks)
    f2ball<<<12288, 256, 0, stream>>>(x, Wq, Wk, Wv, Wo, xb, Wqb);

    // QKV: 256x128-tile minimal-barrier kernel, grid 768 = 3 full CU-rounds
    gemm_bt_256<__hip_bfloat16, true><<<(3 * N / 128) * (M / 256), 512, 0,
                                        stream>>>(
        (const ushort_t*)xb, (const ushort_t*)Wqb, bq, bk, bv, q, M, 3 * N, K);

    attn_mfma<<<16 * Bsz * Hn, 256, 0, stream>>>(
        (const ushort_t*)q, (const ushort_t*)k, (const ushort_t*)v, Opart,
        lpart);

    attn_combine<<<(int)(elems / 8 / 256), 256, 0, stream>>>(Opart, lpart,
                                                             (ushort_t*)ao);

    // out-proj: same minimal-barrier kernel, grid 256 = 1 full CU-round
    gemm_bt_256<float, false><<<(N / 128) * (M / 256), 512, 0, stream>>>(
        (const ushort_t*)ao, (const ushort_t*)Wob, bo, bo, bo, out, M, N, K);
}